// Round 10
// baseline (199.514 us; speedup 1.0000x reference)
//
#include <hip/hip_runtime.h>
#include <stdint.h>

// GAT layer: N nodes, E edges, IN=128 -> H*C=128, H=4 heads, C=32.
// Pipeline (fused, atomic-free partition):
//   k_wprep : Wt[n][k] = bf16(W[k][n])
//   k_gemm  : h(bf16) = bf16(x) @ Wt via mfma_f32_16x16x32_bf16 (Wt in swizzled LDS)
//             + fused alpha (asrc/adst via 16-lane shfl reduce of acc regs)
//             + LDS repack -> wide coalesced h stores (64 B/lane)
//   k_hist  : per-(bucket,block) edge histogram via LDS (bucket = dst>>6, 64 nodes)
//   k_scanA/B/C : hierarchical exclusive scan of cnt2 -> exact (bucket,block) bases
//   k_fill2 : deterministic scatter into ebuf, LDS cursors only (no global atomics)
//   k_agg   : per-bucket counting-sort into LDS; the scatter pass ALSO computes the
//             4 per-head softmax weights p=exp(lrelu(.)) once per edge (packed bf16
//             pairs in LDS). Accumulate loop is then pure LDS-read + h-gather + FMA
//             (no exp/trans ops). Softmax without max-shift: logits bounded,
//             softmax shift-invariant. Single coalesced out write.

#define NBLK 512    // partition blocks
#define BKT 64      // dst nodes per bucket
#define CAP 1792    // max edges sorted in LDS per bucket (mean 1024, +24 sigma)

typedef __bf16 bf16x8 __attribute__((ext_vector_type(8)));
typedef float f32x4 __attribute__((ext_vector_type(4)));

__device__ __forceinline__ float lrelu(float x) { return x >= 0.f ? x : 0.2f * x; }
__device__ __forceinline__ float blo(unsigned u) { return __uint_as_float(u << 16); }
__device__ __forceinline__ float bhi(unsigned u) { return __uint_as_float(u & 0xffff0000u); }
__device__ __forceinline__ unsigned pk2(float a, float b) {
  unsigned short ua = __builtin_bit_cast(unsigned short, (__bf16)a);
  unsigned short ub = __builtin_bit_cast(unsigned short, (__bf16)b);
  return ((unsigned)ub << 16) | ua;
}

__global__ __launch_bounds__(256) void k_wprep(const float* __restrict__ W, __bf16* __restrict__ Wt) {
  int idx = blockIdx.x * 256 + threadIdx.x;   // grid = 64 blocks covers 128*128
  int nn = idx & 127, k = idx >> 7;
  Wt[nn * 128 + k] = (__bf16)W[k * 128 + nn];
}

__global__ __launch_bounds__(256) void k_gemm(const float* __restrict__ x, const __bf16* __restrict__ Wt,
                                              const float* __restrict__ a_src, const float* __restrict__ a_dst,
                                              __bf16* __restrict__ h, float* __restrict__ asrc,
                                              float* __restrict__ adst, int n) {
  __shared__ __align__(16) char Wl[32768];          // Wt[n][k] bf16, XOR-swizzled
  __shared__ __align__(16) __bf16 hbuf[4][16 * 128]; // per-wave bf16 output tile
  int t = threadIdx.x;
  {
    const float4* s4 = (const float4*)Wt;
    for (int i = t; i < 2048; i += 256) {
      int f = i << 4;
      int nr = f >> 8, c = f & 255;
      *(float4*)(Wl + ((nr << 8) | (c ^ ((nr & 7) << 4)))) = s4[i];
    }
  }
  __syncthreads();
  int wv = t >> 6, lane = t & 63;
  int arow = lane & 15, ag = lane >> 4, c15 = lane & 15;
  float as_t[8], ad_t[8];
#pragma unroll
  for (int tile = 0; tile < 8; ++tile) {
    as_t[tile] = a_src[tile * 16 + c15];
    ad_t[tile] = a_dst[tile * 16 + c15];
  }
  int strip = blockIdx.x * 64 + wv * 16;
  int row = strip + arow;
  float4 fa[8];
  if (row < n) {
    const float4* xr = (const float4*)(x + (size_t)row * 128);
#pragma unroll
    for (int q = 0; q < 4; ++q) {
      fa[2 * q]     = xr[q * 8 + ag * 2];
      fa[2 * q + 1] = xr[q * 8 + ag * 2 + 1];
    }
  } else {
#pragma unroll
    for (int q = 0; q < 8; ++q) fa[q] = make_float4(0.f, 0.f, 0.f, 0.f);
  }
  bf16x8 af[4];
#pragma unroll
  for (int q = 0; q < 4; ++q) {
    af[q][0] = (__bf16)fa[2 * q].x;     af[q][1] = (__bf16)fa[2 * q].y;
    af[q][2] = (__bf16)fa[2 * q].z;     af[q][3] = (__bf16)fa[2 * q].w;
    af[q][4] = (__bf16)fa[2 * q + 1].x; af[q][5] = (__bf16)fa[2 * q + 1].y;
    af[q][6] = (__bf16)fa[2 * q + 1].z; af[q][7] = (__bf16)fa[2 * q + 1].w;
  }
  f32x4 acc[8];
#pragma unroll
  for (int tile = 0; tile < 8; ++tile) acc[tile] = (f32x4){0.f, 0.f, 0.f, 0.f};
#pragma unroll
  for (int q = 0; q < 4; ++q) {
    int gb = (q * 64) + (ag << 4);
#pragma unroll
    for (int tile = 0; tile < 8; ++tile) {
      int nn = tile * 16 + c15;
      bf16x8 bf = *(const bf16x8*)(Wl + ((nn << 8) | (gb ^ ((nn & 7) << 4))));
      acc[tile] = __builtin_amdgcn_mfma_f32_16x16x32_bf16(af[q], bf, acc[tile], 0, 0, 0);
    }
  }
  // fused alpha: per (head, r) reduce acc over the 16 c15 lanes
#pragma unroll
  for (int hh = 0; hh < 4; ++hh) {
#pragma unroll
    for (int r = 0; r < 4; ++r) {
      float vps = acc[2 * hh][r] * as_t[2 * hh] + acc[2 * hh + 1][r] * as_t[2 * hh + 1];
      float vpd = acc[2 * hh][r] * ad_t[2 * hh] + acc[2 * hh + 1][r] * ad_t[2 * hh + 1];
#pragma unroll
      for (int m = 1; m < 16; m <<= 1) {
        vps += __shfl_xor(vps, m, 64);
        vpd += __shfl_xor(vpd, m, 64);
      }
      if (c15 == 0) {
        int ro = strip + ag * 4 + r;
        if (ro < n) { asrc[ro * 4 + hh] = vps; adst[ro * 4 + hh] = vpd; }
      }
    }
  }
  // repack acc -> bf16 LDS tile, then wide coalesced store (64 B per lane)
#pragma unroll
  for (int tile = 0; tile < 8; ++tile) {
#pragma unroll
    for (int r = 0; r < 4; ++r)
      hbuf[wv][(ag * 4 + r) * 128 + tile * 16 + c15] = (__bf16)acc[tile][r];
  }
  int rr = lane >> 2, qq = lane & 3;   // lane covers 64 B (32 bf16) of row rr
  int ro = strip + rr;
  if (ro < n) {
    const float4* src = (const float4*)&hbuf[wv][rr * 128 + qq * 32];
    float4* dst = (float4*)(h + (size_t)ro * 128 + qq * 32);
    dst[0] = src[0];
    dst[1] = src[1];
    dst[2] = src[2];
    dst[3] = src[3];
  }
}

// --- atomic-free bucketed edge partition: bucket = dst >> 6 (64 nodes) ---

__global__ __launch_bounds__(256) void k_hist(const int* __restrict__ ei, int* __restrict__ cnt2,
                                              int e, int NB, int CE) {
  __shared__ int hist[2048];
  int t = threadIdx.x, blk = blockIdx.x;
  for (int j = t; j < NB; j += 256) hist[j] = 0;
  __syncthreads();
  int i0 = blk * CE, i1 = min(e, i0 + CE);
  for (int i = i0 + t; i < i1; i += 256) atomicAdd(&hist[ei[e + i] >> 6], 1);
  __syncthreads();
  for (int j = t; j < NB; j += 256) cnt2[j * NBLK + blk] = hist[j];
}

__global__ __launch_bounds__(256) void k_scanA(int* __restrict__ cnt2, int* __restrict__ bsums, int m) {
  __shared__ int wsum[4];
  int t = threadIdx.x, i = blockIdx.x * 256 + t;
  int wv = t >> 6, lane = t & 63;
  int v = (i < m) ? cnt2[i] : 0;
  int sc = v;
#pragma unroll
  for (int ofs = 1; ofs < 64; ofs <<= 1) {
    int u = __shfl_up(sc, ofs, 64);
    if (lane >= ofs) sc += u;
  }
  if (lane == 63) wsum[wv] = sc;
  __syncthreads();
  int base = 0;
  for (int w = 0; w < wv; ++w) base += wsum[w];
  if (i < m) cnt2[i] = base + sc - v;
  if (t == 255) bsums[blockIdx.x] = base + sc;
}

__global__ __launch_bounds__(256) void k_scanB(int* __restrict__ bsums, int nbs) {
  __shared__ int wsum[4];
  int t = threadIdx.x, wv = t >> 6, lane = t & 63;
  int carry = 0;
  for (int c = 0; c < nbs; c += 256) {
    int i = c + t;
    int v = (i < nbs) ? bsums[i] : 0;
    int sc = v;
#pragma unroll
    for (int ofs = 1; ofs < 64; ofs <<= 1) {
      int u = __shfl_up(sc, ofs, 64);
      if (lane >= ofs) sc += u;
    }
    if (lane == 63) wsum[wv] = sc;
    __syncthreads();
    int base = carry;
    for (int w = 0; w < wv; ++w) base += wsum[w];
    if (i < nbs) bsums[i] = base + sc - v;
    carry += wsum[0] + wsum[1] + wsum[2] + wsum[3];
    __syncthreads();
  }
}

__global__ __launch_bounds__(256) void k_scanC(int* __restrict__ cnt2, const int* __restrict__ bsums,
                                               int* __restrict__ boffbg, int m, int NB, int e) {
  int i = blockIdx.x * 256 + threadIdx.x;
  if (i < m) {
    int v = cnt2[i] + bsums[i >> 8];
    cnt2[i] = v;
    if ((i & (NBLK - 1)) == 0) boffbg[i / NBLK] = v;
  }
  if (i == 0) boffbg[NB] = e;
}

__global__ __launch_bounds__(256) void k_fill2(const int* __restrict__ ei, const int* __restrict__ cnt2,
                                               unsigned* __restrict__ ebuf, int e, int NB, int CE) {
  __shared__ int cur[2048];
  int t = threadIdx.x, blk = blockIdx.x;
  for (int j = t; j < NB; j += 256) cur[j] = cnt2[j * NBLK + blk];
  __syncthreads();
  int i0 = blk * CE, i1 = min(e, i0 + CE);
  for (int i = i0 + t; i < i1; i += 256) {
    int s = ei[i], d = ei[e + i];
    int pos = atomicAdd(&cur[d >> 6], 1);    // LDS atomic only
    ebuf[pos] = ((unsigned)(d & 63) << 26) | (unsigned)s;
  }
}

__global__ __launch_bounds__(256) void k_agg(const unsigned* __restrict__ ebuf, const int* __restrict__ boffbg,
                                             const float* __restrict__ asrc, const float* __restrict__ adst,
                                             const unsigned* __restrict__ h32, const float* __restrict__ bias,
                                             float* __restrict__ out, int n) {
  __shared__ int sew[CAP];
  __shared__ __align__(8) uint2 psw[CAP];
  __shared__ __align__(16) float adstl[BKT * 4];
  __shared__ int lcnt[BKT], loff[BKT + 1], lcur[BKT];
  int b = blockIdx.x, t = threadIdx.x;
  int wv = t >> 6, lane = t & 63;
  int s0 = boffbg[b], s1 = boffbg[b + 1];
  int cnt = s1 - s0;
  int d0 = b * BKT;
  bool sorted = (cnt <= CAP);
  if (t < BKT) {
    lcnt[t] = 0;
    if (d0 + t < n) ((float4*)adstl)[t] = ((const float4*)adst)[d0 + t];
    else ((float4*)adstl)[t] = make_float4(0.f, 0.f, 0.f, 0.f);
  }
  __syncthreads();
  if (sorted) {
    for (int j = t; j < cnt; j += 256) atomicAdd(&lcnt[ebuf[s0 + j] >> 26], 1);
    __syncthreads();
    if (wv == 0) {                       // 64-lane scan of bucket-local counts
      int v = lcnt[lane];
      int sc = v;
#pragma unroll
      for (int o = 1; o < 64; o <<= 1) {
        int u = __shfl_up(sc, o, 64);
        if (lane >= o) sc += u;
      }
      loff[lane + 1] = sc;
      if (lane == 0) loff[0] = 0;
      lcur[lane] = sc - v;
    }
    __syncthreads();
    // scatter pass: also compute the 4 per-head weights ONCE per edge
    for (int j = t; j < cnt; j += 256) {
      unsigned u = ebuf[s0 + j];
      int dl = u >> 26;
      int s = (int)(u & 0x03FFFFFFu);
      float4 as = ((const float4*)asrc)[s];
      float p0 = __expf(lrelu(as.x + adstl[dl * 4 + 0]));
      float p1 = __expf(lrelu(as.y + adstl[dl * 4 + 1]));
      float p2 = __expf(lrelu(as.z + adstl[dl * 4 + 2]));
      float p3 = __expf(lrelu(as.w + adstl[dl * 4 + 3]));
      int pos = atomicAdd(&lcur[dl], 1);
      sew[pos] = s;
      psw[pos] = make_uint2(pk2(p0, p1), pk2(p2, p3));
    }
    __syncthreads();
  }
  int head = lane >> 4;
  bool hodd = (head & 1), hhi = (head & 2);
  float2 bb = ((const float2*)bias)[lane];
  for (int nd = wv; nd < BKT; nd += 4) {
    int d = d0 + nd;
    if (d >= n) break;
    float adh = adstl[nd * 4 + head];
    float pself = __expf(lrelu(asrc[d * 4 + head] + adh));
    unsigned su = h32[((unsigned)d << 6) + lane];
    float acc0 = pself * blo(su), acc1 = pself * bhi(su), dtot = pself;
    if (sorted) {
      int j = loff[nd], j1 = loff[nd + 1];
      for (; j + 4 <= j1; j += 4) {
        int sA = sew[j], sB = sew[j + 1], sC = sew[j + 2], sD = sew[j + 3];
        uint2 wA = psw[j], wB = psw[j + 1], wC = psw[j + 2], wD = psw[j + 3];
        unsigned uA = h32[((unsigned)sA << 6) + lane];
        unsigned uB = h32[((unsigned)sB << 6) + lane];
        unsigned uC = h32[((unsigned)sC << 6) + lane];
        unsigned uD = h32[((unsigned)sD << 6) + lane];
        unsigned vA = hhi ? wA.y : wA.x, vB = hhi ? wB.y : wB.x;
        unsigned vC = hhi ? wC.y : wC.x, vD = hhi ? wD.y : wD.x;
        float pA = hodd ? bhi(vA) : blo(vA);
        float pB = hodd ? bhi(vB) : blo(vB);
        float pC = hodd ? bhi(vC) : blo(vC);
        float pD = hodd ? bhi(vD) : blo(vD);
        dtot += (pA + pB) + (pC + pD);
        acc0 += pA * blo(uA) + pB * blo(uB) + pC * blo(uC) + pD * blo(uD);
        acc1 += pA * bhi(uA) + pB * bhi(uB) + pC * bhi(uC) + pD * bhi(uD);
      }
      for (; j < j1; ++j) {
        int s = sew[j];
        uint2 w = psw[j];
        unsigned u = h32[((unsigned)s << 6) + lane];
        unsigned v = hhi ? w.y : w.x;
        float p = hodd ? bhi(v) : blo(v);
        dtot += p;
        acc0 += p * blo(u);
        acc1 += p * bhi(u);
      }
    } else {                              // overflow fallback (never for uniform input)
      for (int j = s0; j < s1; ++j) {
        unsigned u = ebuf[j];
        if ((int)(u >> 26) != nd) continue;
        int s = (int)(u & 0x03FFFFFFu);
        unsigned hu = h32[((unsigned)s << 6) + lane];
        float p = __expf(lrelu(asrc[s * 4 + head] + adh));
        dtot += p;
        acc0 += p * blo(hu);
        acc1 += p * bhi(hu);
      }
    }
    float inv = 1.f / dtot;
    ((float2*)(out + (size_t)d * 128))[lane] = make_float2(acc0 * inv + bb.x, acc1 * inv + bb.y);
  }
}

extern "C" void kernel_launch(void* const* d_in, const int* in_sizes, int n_in,
                              void* d_out, int out_size, void* d_ws, size_t ws_size,
                              hipStream_t stream) {
  const float* x     = (const float*)d_in[0];
  const int*   ei    = (const int*)d_in[1];
  const float* W     = (const float*)d_in[2];
  const float* a_src = (const float*)d_in[3];
  const float* a_dst = (const float*)d_in[4];
  const float* bias  = (const float*)d_in[5];
  float* out = (float*)d_out;

  int n = in_sizes[0] / 128;   // IN = 128
  int e = in_sizes[1] / 2;
  int NB = (n + BKT - 1) / BKT;   // dst buckets of 64 nodes
  int m = NB * NBLK;
  int gridA = (m + 255) / 256;
  int CE = (e + NBLK - 1) / NBLK;

  char* ws = (char*)d_ws;
  size_t ofs = 0;
  auto alloc = [&](size_t bytes) { void* p = ws + ofs; ofs = (ofs + bytes + 15) & ~(size_t)15; return p; };
  __bf16* h      = (__bf16*)alloc((size_t)n * 128 * sizeof(__bf16));    // 25.6 MB
  unsigned* h32  = (unsigned*)h;
  float* asrc    = (float*)alloc((size_t)n * 4 * sizeof(float));
  float* adst    = (float*)alloc((size_t)n * 4 * sizeof(float));
  int* cnt2      = (int*)alloc((size_t)m * sizeof(int));                // 3.2 MB
  int* bsums     = (int*)alloc((size_t)gridA * sizeof(int));
  int* boffbg    = (int*)alloc((size_t)(NB + 1) * sizeof(int));
  unsigned* ebuf = (unsigned*)alloc((size_t)e * sizeof(unsigned));      // 6.4 MB
  __bf16* Wt     = (__bf16*)alloc((size_t)128 * 128 * sizeof(__bf16));  // 32 KB

  hipLaunchKernelGGL(k_wprep, dim3(64), dim3(256), 0, stream, W, Wt);
  hipLaunchKernelGGL(k_gemm, dim3((n + 63) / 64), dim3(256), 0, stream,
                     x, Wt, a_src, a_dst, h, asrc, adst, n);
  hipLaunchKernelGGL(k_hist, dim3(NBLK), dim3(256), 0, stream, ei, cnt2, e, NB, CE);
  hipLaunchKernelGGL(k_scanA, dim3(gridA), dim3(256), 0, stream, cnt2, bsums, m);
  hipLaunchKernelGGL(k_scanB, dim3(1), dim3(256), 0, stream, bsums, gridA);
  hipLaunchKernelGGL(k_scanC, dim3(gridA), dim3(256), 0, stream, cnt2, bsums, boffbg, m, NB, e);
  hipLaunchKernelGGL(k_fill2, dim3(NBLK), dim3(256), 0, stream, ei, cnt2, ebuf, e, NB, CE);
  hipLaunchKernelGGL(k_agg, dim3(NB), dim3(256), 0, stream,
                     ebuf, boffbg, asrc, adst, h32, bias, out, n);
}